// Round 19
// baseline (133.122 us; speedup 1.0000x reference)
//
#include <hip/hip_runtime.h>

// Problem constants (reference: B=16384, DIM_X=2048, K=128)
#define BB 16384
#define DD 2048
#define KK 128
#define NT 64            // DD / 32 k-steps
#define RPB 16           // rows per block
#define NBLK 1024        // blocks (16 rows each)
#define DELTA 8e-3f      // argmax gap below which we re-resolve in fp64
#define FCAP 2048        // flag-list capacity (entries of 132 floats)

typedef __attribute__((ext_vector_type(8))) short  bf16x8;
typedef __attribute__((ext_vector_type(4))) float  f32x4;
typedef __attribute__((ext_vector_type(4))) unsigned int u32x4;

union V16 { u32x4 u; f32x4 f; bf16x8 s; };

// ---------------------------------------------------------------------------
// Prep (coalesced): RNE-round enc_W and dec_W to bf16, laid out in MFMA
// B-fragment order: element ((t*8+ct)*64+l)*8+j <-> W[ct*16+(l&15)][t*32+(l>>4)*8+j].
// 128 blocks = sel(2) x ct(8) x ktile(8); each stages a 16x256 f32 tile via
// LDS (1KB-contiguous reads, contiguous 16B fragment writes).
// Also zeroes the loss/accuracy accumulators and the flag counter.
// ---------------------------------------------------------------------------
__global__ __launch_bounds__(256) void prep_kernel(
    const float* __restrict__ encW, const float* __restrict__ decW,
    unsigned short* __restrict__ wEh, unsigned short* __restrict__ wDh,
    float* __restrict__ out, unsigned int* __restrict__ counter)
{
  __shared__ float sw[16][260];
  const int bid = blockIdx.x;
  const int tid = threadIdx.x;
  if (bid == 0 && tid == 0) { *counter = 0u; out[2*BB] = 0.f; out[2*BB+1] = 0.f; }
  const int sel = bid >> 6, rem = bid & 63;
  const int ct = rem >> 3, kt = rem & 7;
  const float* W = sel ? decW : encW;
  unsigned short* oh = sel ? wDh : wEh;

  {
    const int row = tid >> 4, seg = tid & 15;
    const float* src = W + (size_t)(ct * 16 + row) * DD + kt * 256 + seg * 16;
#pragma unroll
    for (int i = 0; i < 4; ++i)
      *(f32x4*)&sw[row][seg * 16 + i * 4] = *(const f32x4*)(src + i * 4);
  }
  __syncthreads();

  const int l = tid & 63, wv = tid >> 6;
#pragma unroll
  for (int h = 0; h < 2; ++h) {
    const int tt = wv * 2 + h;
    const int t  = kt * 8 + tt;
    const float* sp = &sw[l & 15][tt * 32 + ((l >> 4) << 3)];
    V16 vh;
#pragma unroll
    for (int p = 0; p < 4; ++p) {
      unsigned hu[2];
#pragma unroll
      for (int q = 0; q < 2; ++q) {
        unsigned u  = __float_as_uint(sp[p * 2 + q]);
        unsigned rh = u + 0x7FFFu + ((u >> 16) & 1u);   // RNE to bf16
        hu[q] = (rh >> 16) & 0xFFFFu;
      }
      vh.u[p] = (hu[1] << 16) | hu[0];
    }
    *(u32x4*)(oh + ((size_t)(t * 8 + ct) * 64 + l) * 8) = vh.u;
  }
}

// ---------------------------------------------------------------------------
// Main: BARRIER-FREE K-loop (the final structural A/B). 1024 blocks x 256
// threads (4 waves; block = 16 rows x 128 cols; wave w owns col-tiles 2w,2w+1).
// NO LDS and NO __syncthreads/s_waitcnt in the K-loop: A (x) loaded per-wave
// direct global->VGPR in MFMA fragment layout; B direct global->VGPR (L1);
// both register-double-buffered one kstep ahead; bf16 hi/lo split on read.
// Waves free-run -- if R11-R18's ~2000cy/kstep residual was barrier-lockstep
// amplification, this collapses it; if it is intrinsic dependent-latency, time
// stays ~77us and the session ships R12/R18 as the practical ceiling.
// LDS used only by the epilogue (one sync). Pool padded to 32KB -> 5 blocks/CU
// = 20 waves/CU (5/SIMD; VGPR budget ~102, live ~92, no spill per R8-R18 model).
// ---------------------------------------------------------------------------
__global__ __launch_bounds__(256)
void main_kernel(
    const float* __restrict__ x, const float* __restrict__ y,
    const float* __restrict__ encb, const float* __restrict__ decb,
    const unsigned short* __restrict__ wEh, const unsigned short* __restrict__ wDh,
    float* __restrict__ out, unsigned int* __restrict__ counter,
    float* __restrict__ list)
{
  __shared__ __align__(16) unsigned char pool[32768];   // epilogue only; 5 blocks/CU
  const int tid = threadIdx.x;
  const int w = tid >> 6, l = tid & 63;
  const int rbase = blockIdx.x * RPB;

  // A direct-load pointer (MFMA fragment layout): lane l -> row l&15, k (l>>4)*8
  const float* xp = x + (size_t)(rbase + (l & 15)) * DD + ((l >> 4) << 3);

  // B fragment sources; wave w covers col-tiles 2w, 2w+1
  const unsigned short* gE = wEh + (size_t)(w * 1024) + l * 8;
  const unsigned short* gD = wDh + (size_t)(w * 1024) + l * 8;

  f32x4 accE[2], accD[2];
  const f32x4 zero4 = {0.f, 0.f, 0.f, 0.f};
#pragma unroll
  for (int ct = 0; ct < 2; ++ct) { accE[ct] = zero4; accD[ct] = zero4; }

#define LDB(base, t, off) (*(const bf16x8*)((base) + (size_t)(t) * 4096 + (off)))
#define MFMA(a, b, c) __builtin_amdgcn_mfma_f32_16x16x32_bf16(a, b, c, 0, 0, 0)

  // register double-buffer: current (a0,a1,E0,E1,D0,D1), next (n*, m*)
  f32x4 a0 = *(const f32x4*)xp;
  f32x4 a1 = *(const f32x4*)(xp + 4);
  bf16x8 E0 = LDB(gE, 0, 0), E1 = LDB(gE, 0, 512);
  bf16x8 D0 = LDB(gD, 0, 0), D1 = LDB(gD, 0, 512);

  for (int t = 0; t < NT; ++t) {
    f32x4 na0, na1;
    bf16x8 nE0, nE1, nD0, nD1;
    if (t + 1 < NT) {
      const float* p = xp + (size_t)(t + 1) * 32;
      na0 = *(const f32x4*)p;
      na1 = *(const f32x4*)(p + 4);
      nE0 = LDB(gE, t + 1, 0); nE1 = LDB(gE, t + 1, 512);
      nD0 = LDB(gD, t + 1, 0); nD1 = LDB(gD, t + 1, 512);
    }
    // split a0,a1 -> ah (truncate), al (RNE of residual)
    float fa[8] = {a0[0],a0[1],a0[2],a0[3],a1[0],a1[1],a1[2],a1[3]};
    V16 vh, vl;
#pragma unroll
    for (int p = 0; p < 4; ++p) {
      unsigned u0 = __float_as_uint(fa[2*p]);
      unsigned u1 = __float_as_uint(fa[2*p+1]);
      vh.u[p] = (u0 >> 16) | (u1 & 0xFFFF0000u);
      float r0 = fa[2*p]   - __uint_as_float(u0 & 0xFFFF0000u);
      float r1 = fa[2*p+1] - __uint_as_float(u1 & 0xFFFF0000u);
      vl.u[p] = (__float_as_uint(r0) >> 16) | (__float_as_uint(r1) & 0xFFFF0000u);
    }
    bf16x8 ah = vh.s, al = vl.s;
    __builtin_amdgcn_s_setprio(1);
    accE[0] = MFMA(ah, E0, accE[0]);
    accE[1] = MFMA(ah, E1, accE[1]);
    accD[0] = MFMA(ah, D0, accD[0]);
    accD[1] = MFMA(ah, D1, accD[1]);
    accE[0] = MFMA(al, E0, accE[0]);
    accE[1] = MFMA(al, E1, accE[1]);
    __builtin_amdgcn_s_setprio(0);
    if (t + 1 < NT) {
      a0 = na0; a1 = na1;
      E0 = nE0; E1 = nE1; D0 = nD0; D1 = nD1;
    }
  }
#undef MFMA
#undef LDB

  // ---------------- epilogue (LDS; one sync) ----------------
  float* sT  = (float*)pool;                  // [16][132] dec-GEMM results
  float* sS  = (float*)(pool + 8448);         // [16][128] enc s-values (biased)
  float* sm1 = (float*)(pool + 16640);        // [16][4] top-1
  float* sm2 = (float*)(pool + 16896);        // [16][4] top-2
  int*   si1 = (int*)  (pool + 17152);        // [16][4] argmax col

  {
    const int q = l >> 4, cc = l & 15;
    const int col0 = w * 32 + cc;
    const int col1 = col0 + 16;
#pragma unroll
    for (int ct = 0; ct < 2; ++ct) {
      const int col = w * 32 + ct * 16 + cc;
#pragma unroll
      for (int i = 0; i < 4; ++i)
        sT[(q * 4 + i) * 132 + col] = accD[ct][i];
    }
    const float b0 = encb[col0], b1 = encb[col1];
    float m1v[4], m2v[4]; int i1v[4];
#pragma unroll
    for (int i = 0; i < 4; ++i) {
      const int row = q * 4 + i;
      float v0 = accE[0][i] + b0;
      float v1 = accE[1][i] + b1;
      sS[row * 128 + col0] = v0;
      sS[row * 128 + col1] = v1;
      if (v0 >= v1) { m1v[i] = v0; m2v[i] = v1; i1v[i] = col0; }
      else          { m1v[i] = v1; m2v[i] = v0; i1v[i] = col1; }
    }
#pragma unroll
    for (int d = 1; d < 16; d <<= 1) {
#pragma unroll
      for (int i = 0; i < 4; ++i) {
        float om1 = __shfl_xor(m1v[i], d);
        float om2 = __shfl_xor(m2v[i], d);
        int   oi  = __shfl_xor(i1v[i], d);
        if (om1 > m1v[i] || (om1 == m1v[i] && oi < i1v[i])) {
          m2v[i] = fmaxf(m1v[i], om2); m1v[i] = om1; i1v[i] = oi;
        } else {
          m2v[i] = fmaxf(m2v[i], om1);
        }
      }
    }
    if (cc == 0) {
#pragma unroll
      for (int i = 0; i < 4; ++i) {
        const int row = q * 4 + i;
        sm1[row * 4 + w] = m1v[i];
        sm2[row * 4 + w] = m2v[i];
        si1[row * 4 + w] = i1v[i];
      }
    }
  }
  __syncthreads();

  float lossAcc = 0.f, accAcc = 0.f;
  if (tid < RPB) {
    const int row = tid, R = rbase + row;
    float m1 = -3.4e38f, m2 = -3.4e38f; int i1 = 0;
#pragma unroll
    for (int g = 0; g < 4; ++g) {
      float a1g = sm1[row * 4 + g], a2g = sm2[row * 4 + g];
      int ai = si1[row * 4 + g];
      if (a1g > m1) { m2 = fmaxf(m1, a2g); m1 = a1g; i1 = ai; }
      else          { m2 = fmaxf(m2, a1g); }
    }
    float yh = sT[row * 132 + i1] + decb[i1];
    out[R]      = yh;
    out[BB + R] = (float)i1;
    if (m1 - m2 < DELTA) {                     // near-tie: fp64 re-resolve later
      unsigned p = atomicAdd(counter, 1u);
      if (p < (unsigned)FCAP) {
        float* ent = list + (size_t)p * 132;
        ((unsigned*)ent)[0] = (unsigned)R;
        const f32x4* sr = (const f32x4*)(sS + row * 128);
        f32x4* dst = (f32x4*)(ent + 4);
#pragma unroll
        for (int j = 0; j < 32; ++j) dst[j] = sr[j];
      }
    }
    float yv = y[R];
    float d  = yh - yv;
    lossAcc = d * d;
    float sg = (yh > 0.f) ? 1.f : ((yh < 0.f) ? -1.f : 0.f);
    accAcc = (sg == yv) ? 1.f : 0.f;
  }
#pragma unroll
  for (int d = 1; d < 64; d <<= 1) {
    lossAcc += __shfl_xor(lossAcc, d);
    accAcc  += __shfl_xor(accAcc, d);
  }
  if (tid == 0) {
    atomicAdd(&out[2*BB],     lossAcc * (1.f / BB));
    atomicAdd(&out[2*BB + 1], accAcc  * (1.f / BB));
  }
}

// ---------------------------------------------------------------------------
// Fixup v2: one wave per flagged row. Reads the dumped approx s-row, selects
// candidate cols within (m1 - 2*DELTA), recomputes ONLY those (typically 1-3)
// in fp64 (coalesced 1KB loads), picks the true argmax, recomputes y_hat in
// fp64, patches out + loss/accuracy atomics.
// ---------------------------------------------------------------------------
__global__ __launch_bounds__(64) void fixup_kernel(
    const float* __restrict__ x, const float* __restrict__ y,
    const float* __restrict__ encW, const float* __restrict__ encb,
    const float* __restrict__ decW, const float* __restrict__ decb,
    float* __restrict__ out,
    const unsigned int* __restrict__ counter, const float* __restrict__ list)
{
  int n = (int)*counter;
  if (n > FCAP) n = FCAP;
  const int l = threadIdx.x;
  for (int e = blockIdx.x; e < n; e += gridDim.x) {
    const float* ent = list + (size_t)e * 132;
    const int R = (int)((const unsigned*)ent)[0];
    const float s0 = ent[4 + 2 * l], s1 = ent[5 + 2 * l];
    float m = fmaxf(s0, s1);
#pragma unroll
    for (int d = 1; d < 64; d <<= 1) m = fmaxf(m, __shfl_xor(m, d));
    const float win = m - 2.0f * DELTA;
    unsigned long long mm0 = __ballot(s0 >= win);
    unsigned long long mm1 = __ballot(s1 >= win);
    const float* xr = x + (size_t)R * DD;
    double best = -1e300; int bk = KK;
    while (mm0 | mm1) {
      int c;
      if (mm0) { int b = __builtin_ctzll(mm0); mm0 &= mm0 - 1; c = 2 * b; }
      else     { int b = __builtin_ctzll(mm1); mm1 &= mm1 - 1; c = 2 * b + 1; }
      const float* wp = encW + (size_t)c * DD;
      double s = 0.0;
#pragma unroll
      for (int j = 0; j < 8; ++j) {
        f32x4 wv = *(const f32x4*)(wp + j * 256 + l * 4);
        f32x4 xv = *(const f32x4*)(xr + j * 256 + l * 4);
        s = fma((double)xv[0], (double)wv[0], s);
        s = fma((double)xv[1], (double)wv[1], s);
        s = fma((double)xv[2], (double)wv[2], s);
        s = fma((double)xv[3], (double)wv[3], s);
      }
#pragma unroll
      for (int d = 1; d < 64; d <<= 1) s += __shfl_xor(s, d);
      s += (double)encb[c];
      if (s > best || (s == best && c < bk)) { best = s; bk = c; }
    }
    // dec dot in fp64
    const float* dr = decW + (size_t)bk * DD;
    double t = 0.0;
#pragma unroll
    for (int j = 0; j < 8; ++j) {
      f32x4 wv = *(const f32x4*)(dr + j * 256 + l * 4);
      f32x4 xv = *(const f32x4*)(xr + j * 256 + l * 4);
      t = fma((double)xv[0], (double)wv[0], t);
      t = fma((double)xv[1], (double)wv[1], t);
      t = fma((double)xv[2], (double)wv[2], t);
      t = fma((double)xv[3], (double)wv[3], t);
    }
#pragma unroll
    for (int d = 1; d < 64; d <<= 1) t += __shfl_xor(t, d);
    if (l == 0) {
      float yh = (float)(t + (double)decb[bk]);
      float yv = y[R];
      float old = out[R];
      float dn = yh - yv, dol = old - yv;
      atomicAdd(&out[2*BB], (dn*dn - dol*dol) * (1.f / BB));
      float sgn = (yh  > 0.f) ? 1.f : ((yh  < 0.f) ? -1.f : 0.f);
      float sgo = (old > 0.f) ? 1.f : ((old < 0.f) ? -1.f : 0.f);
      float mn = (sgn == yv) ? 1.f : 0.f;
      float mo = (sgo == yv) ? 1.f : 0.f;
      atomicAdd(&out[2*BB + 1], (mn - mo) * (1.f / BB));
      out[R]      = yh;
      out[BB + R] = (float)bk;
    }
  }
}

extern "C" void kernel_launch(void* const* d_in, const int* in_sizes, int n_in,
                              void* d_out, int out_size, void* d_ws, size_t ws_size,
                              hipStream_t stream)
{
  const float* x    = (const float*)d_in[0];
  const float* y    = (const float*)d_in[1];
  // d_in[2] = z (unused by the reference computation)
  const float* encW = (const float*)d_in[3];
  const float* encb = (const float*)d_in[4];
  const float* decW = (const float*)d_in[5];   // [1,128,2048] -> row-major [128][2048]
  const float* decb = (const float*)d_in[6];
  float* out = (float*)d_out;

  unsigned char* ws = (unsigned char*)d_ws;
  unsigned short* wEh = (unsigned short*)ws;                 // 512 KB
  unsigned short* wDh = (unsigned short*)(ws + 524288);      // 512 KB
  unsigned int* counter = (unsigned int*)(ws + 1048576);
  float* list = (float*)(ws + 1048592);                      // FCAP x 132 floats

  prep_kernel<<<128, 256, 0, stream>>>(encW, decW, wEh, wDh, out, counter);
  main_kernel<<<NBLK, 256, 0, stream>>>(x, y, encb, decb, wEh, wDh,
                                        out, counter, list);
  fixup_kernel<<<512, 64, 0, stream>>>(x, y, encW, encb, decW, decb,
                                       out, counter, list);
}

// Round 20
// 84.019 us; speedup vs baseline: 1.5844x; 1.5844x over previous
//
#include <hip/hip_runtime.h>

// Problem constants (reference: B=16384, DIM_X=2048, K=128)
#define BB 16384
#define DD 2048
#define KK 128
#define NT 64            // DD / 32 k-steps
#define NCHK 32          // chunks of 2 k-steps
#define RPB 64           // rows per block
#define NBLK 256         // blocks (1 per CU)
#define DELTA 8e-3f      // argmax gap below which we re-resolve in fp64
#define BUFS 49152       // per-chunk buffer: xhi 8K | xlo 8K | E 16K | D 16K
#define FCAP 2048        // flag-list capacity (entries of 132 floats)

typedef __attribute__((ext_vector_type(8))) short  bf16x8;
typedef __attribute__((ext_vector_type(4))) float  f32x4;
typedef __attribute__((ext_vector_type(4))) unsigned int u32x4;

union V16 { u32x4 u; f32x4 f; bf16x8 s; };

__device__ __forceinline__ void gld16(const void* g, void* l) {
  __builtin_amdgcn_global_load_lds(
      (const __attribute__((address_space(1))) void*)g,
      (__attribute__((address_space(3))) void*)l, 16, 0, 0);
}

// ---------------------------------------------------------------------------
// Prep (coalesced): RNE-round enc_W and dec_W to bf16, laid out in MFMA
// B-fragment order: element ((t*8+ct)*64+l)*8+j <-> W[ct*16+(l&15)][t*32+(l>>4)*8+j].
// 128 blocks = sel(2) x ct(8) x ktile(8); each stages a 16x256 f32 tile via
// LDS (1KB-contiguous reads, contiguous 16B fragment writes).
// Also zeroes the loss/accuracy accumulators and the flag counter.
// ---------------------------------------------------------------------------
__global__ __launch_bounds__(256) void prep_kernel(
    const float* __restrict__ encW, const float* __restrict__ decW,
    unsigned short* __restrict__ wEh, unsigned short* __restrict__ wDh,
    float* __restrict__ out, unsigned int* __restrict__ counter)
{
  __shared__ float sw[16][260];
  const int bid = blockIdx.x;
  const int tid = threadIdx.x;
  if (bid == 0 && tid == 0) { *counter = 0u; out[2*BB] = 0.f; out[2*BB+1] = 0.f; }
  const int sel = bid >> 6, rem = bid & 63;
  const int ct = rem >> 3, kt = rem & 7;
  const float* W = sel ? decW : encW;
  unsigned short* oh = sel ? wDh : wEh;

  {
    const int row = tid >> 4, seg = tid & 15;
    const float* src = W + (size_t)(ct * 16 + row) * DD + kt * 256 + seg * 16;
#pragma unroll
    for (int i = 0; i < 4; ++i)
      *(f32x4*)&sw[row][seg * 16 + i * 4] = *(const f32x4*)(src + i * 4);
  }
  __syncthreads();

  const int l = tid & 63, wv = tid >> 6;
#pragma unroll
  for (int h = 0; h < 2; ++h) {
    const int tt = wv * 2 + h;
    const int t  = kt * 8 + tt;
    const float* sp = &sw[l & 15][tt * 32 + ((l >> 4) << 3)];
    V16 vh;
#pragma unroll
    for (int p = 0; p < 4; ++p) {
      unsigned hu[2];
#pragma unroll
      for (int q = 0; q < 2; ++q) {
        unsigned u  = __float_as_uint(sp[p * 2 + q]);
        unsigned rh = u + 0x7FFFu + ((u >> 16) & 1u);   // RNE to bf16
        hu[q] = (rh >> 16) & 0xFFFFu;
      }
      vh.u[p] = (hu[1] << 16) | hu[0];
    }
    *(u32x4*)(oh + ((size_t)(t * 8 + ct) * 64 + l) * 8) = vh.u;
  }
}

// ---------------------------------------------------------------------------
// Main fused kernel: 256 blocks x 512 threads (1 block/CU, 8 waves).
// Minimal-traffic decomposition: wave w = (wr = w>>2) in 2 row-groups x
// (wcg = w&3) in 4 col-groups; rt=2 (rows wr*32..+31), ct=2 (cols wcg*32..+31).
// Per-kstep operand traffic/CU = A(8KB)x4 + B(16KB)x2 = 64KB, ALL through LDS.
// B staged per-chunk via global_load_lds DMA (single shared copy, contiguous
// 1KB frags, dense conflict-free reads). x split to bf16 hi/lo at stage into
// XOR-swizzled planes. Chunk = 2 ksteps, double-buffered 48KB buffers (96KB
// LDS -> 1 block/CU -> 2 waves/SIMD -> 256-VGPR RA budget, no spills).
// Per wave/kstep: 4 A ds_read + 4 B ds_read + 12 MFMA.
// [Session-best configuration: 83.8us (R12) / 84.4us (R18) total measured.]
// ---------------------------------------------------------------------------
__global__ __launch_bounds__(512)
void main_kernel(
    const float* __restrict__ x, const float* __restrict__ y,
    const float* __restrict__ encb, const float* __restrict__ decb,
    const unsigned short* __restrict__ wEh, const unsigned short* __restrict__ wDh,
    float* __restrict__ out, unsigned int* __restrict__ counter,
    float* __restrict__ list)
{
  __shared__ __align__(16) unsigned char pool[98304];
  const int tid = threadIdx.x;
  const int w = tid >> 6, l = tid & 63;
  const int wr = w >> 2, wcg = w & 3;
  const int rbase = blockIdx.x * RPB;

  // x stage addressing: thread -> (row srow, 16B seg of 8 floats)
  const int srow = tid >> 3, seg = tid & 7;
  const float* gXc = x + (size_t)(rbase + srow) * DD + seg * 8;
  const int woff = srow * 128 + ((seg ^ (srow & 7)) << 4);   // hi-plane byte off

  // A-fragment LDS offsets
  int rowb[2];
#pragma unroll
  for (int rt = 0; rt < 2; ++rt)
    rowb[rt] = (wr * 32 + rt * 16 + (l & 15)) * 128;
  int blkb[2];
#pragma unroll
  for (int tt = 0; tt < 2; ++tt)
    blkb[tt] = ((tt * 4 + (l >> 4)) ^ (l & 7)) << 4;

  // B-fragment LDS offset (within E or D plane of a kstep): dense 1KB frags
  const int bfo = wcg * 2048 + (l << 4);

  f32x4 accE[2][2], accD[2][2];
  const f32x4 zero4 = {0.f, 0.f, 0.f, 0.f};
#pragma unroll
  for (int rt = 0; rt < 2; ++rt)
#pragma unroll
    for (int ct = 0; ct < 2; ++ct) { accE[rt][ct] = zero4; accD[rt][ct] = zero4; }

  auto WRX = [&](int nb, f32x4 A, f32x4 Bv) {
    float fa[8] = {A[0],A[1],A[2],A[3],Bv[0],Bv[1],Bv[2],Bv[3]};
    V16 vh, vl;
#pragma unroll
    for (int p = 0; p < 4; ++p) {
      unsigned u0 = __float_as_uint(fa[2*p]);
      unsigned u1 = __float_as_uint(fa[2*p+1]);
      vh.u[p] = (u0 >> 16) | (u1 & 0xFFFF0000u);
      float r0 = fa[2*p]   - __uint_as_float(u0 & 0xFFFF0000u);
      float r1 = fa[2*p+1] - __uint_as_float(u1 & 0xFFFF0000u);
      vl.u[p] = (__float_as_uint(r0) >> 16) | (__float_as_uint(r1) & 0xFFFF0000u);
    }
    unsigned char* bp = pool + nb + woff;
    *(u32x4*)bp           = vh.u;
    *(u32x4*)(bp + 8192)  = vl.u;
  };

  // B DMA: 4 gld16/thread/chunk -> E(kstep0), E(kstep1), D(k0), D(k1)
  auto DMAB = [&](int nb, int c) {
    const unsigned short* eb = wEh + (size_t)(2 * c) * 4096 + tid * 8;
    const unsigned short* db = wDh + (size_t)(2 * c) * 4096 + tid * 8;
    gld16(eb,        pool + nb + 16384 + w * 1024);
    gld16(eb + 4096, pool + nb + 24576 + w * 1024);
    gld16(db,        pool + nb + 32768 + w * 1024);
    gld16(db + 4096, pool + nb + 40960 + w * 1024);
  };

#define MFMA(a, b, c) __builtin_amdgcn_mfma_f32_16x16x32_bf16(a, b, c, 0, 0, 0)
#define KSTEP(cbase, tt) do {                                                    \
    const unsigned char* bp = pool + (cbase);                                    \
    const unsigned char* bb = bp + 16384 + (tt) * 8192 + bfo;                    \
    bf16x8 E0 = *(const bf16x8*)bb;                                              \
    bf16x8 E1 = *(const bf16x8*)(bb + 1024);                                     \
    bf16x8 D0 = *(const bf16x8*)(bb + 16384);                                    \
    bf16x8 D1 = *(const bf16x8*)(bb + 16384 + 1024);                             \
    _Pragma("unroll")                                                            \
    for (int rt = 0; rt < 2; ++rt) {                                             \
      const unsigned char* ap = bp + rowb[rt] + blkb[tt];                        \
      bf16x8 ah = *(const bf16x8*)ap;                                            \
      bf16x8 al = *(const bf16x8*)(ap + 8192);                                   \
      accE[rt][0] = MFMA(ah, E0, accE[rt][0]);                                   \
      accE[rt][1] = MFMA(ah, E1, accE[rt][1]);                                   \
      accD[rt][0] = MFMA(ah, D0, accD[rt][0]);                                   \
      accD[rt][1] = MFMA(ah, D1, accD[rt][1]);                                   \
      accE[rt][0] = MFMA(al, E0, accE[rt][0]);                                   \
      accE[rt][1] = MFMA(al, E1, accE[rt][1]);                                   \
    }                                                                            \
  } while (0)

  // prologue: chunk 0 -> buffer 0
  {
    f32x4 xA = *(const f32x4*)gXc;
    f32x4 xB = *(const f32x4*)(gXc + 4);
    DMAB(0, 0);
    WRX(0, xA, xB);
    asm volatile("s_waitcnt vmcnt(0) lgkmcnt(0)" ::: "memory");
    __builtin_amdgcn_s_barrier();
  }

  for (int c = 0; c < NCHK; ++c) {
    const int cb = (c & 1) * BUFS;
    const int nb = cb ^ BUFS;
    f32x4 xA, xB;
    if (c + 1 < NCHK) {
      const float* p = gXc + (size_t)(c + 1) * 64;
      xA = *(const f32x4*)p; xB = *(const f32x4*)(p + 4);
      DMAB(nb, c + 1);                      // DMA issued early, retires under compute
    }
    __builtin_amdgcn_s_setprio(1);
    KSTEP(cb, 0);
    KSTEP(cb, 1);
    __builtin_amdgcn_s_setprio(0);
    if (c + 1 < NCHK) WRX(nb, xA, xB);      // x latency hidden by this chunk
    asm volatile("s_waitcnt vmcnt(0) lgkmcnt(0)" ::: "memory");
    __builtin_amdgcn_s_barrier();
  }
#undef KSTEP
#undef MFMA

  // ---------------- epilogue (overlays the staging pool) ----------------
  float* sT  = (float*)pool;                  // [64][132] dec-GEMM results
  float* sS  = (float*)(pool + 33792);        // [64][128] enc s-values (biased)
  float* sm1 = (float*)(pool + 66560);        // [64][4] top-1
  float* sm2 = (float*)(pool + 67584);        // [64][4] top-2
  int*   si1 = (int*)  (pool + 68608);        // [64][4] argmax col

  {
    const int q = l >> 4, cc = l & 15;
    const int col0 = wcg * 32 + cc;
    const int col1 = col0 + 16;
#pragma unroll
    for (int rt = 0; rt < 2; ++rt)
#pragma unroll
      for (int ct = 0; ct < 2; ++ct) {
        const int col = wcg * 32 + ct * 16 + cc;
#pragma unroll
        for (int i = 0; i < 4; ++i)
          sT[(wr * 32 + rt * 16 + q * 4 + i) * 132 + col] = accD[rt][ct][i];
      }
    const float b0 = encb[col0], b1 = encb[col1];
    float m1v[8], m2v[8]; int i1v[8];
#pragma unroll
    for (int rt = 0; rt < 2; ++rt)
#pragma unroll
      for (int i = 0; i < 4; ++i) {
        const int j = rt * 4 + i;
        const int row = wr * 32 + rt * 16 + q * 4 + i;
        float v0 = accE[rt][0][i] + b0;
        float v1 = accE[rt][1][i] + b1;
        sS[row * 128 + col0] = v0;
        sS[row * 128 + col1] = v1;
        if (v0 >= v1) { m1v[j] = v0; m2v[j] = v1; i1v[j] = col0; }
        else          { m1v[j] = v1; m2v[j] = v0; i1v[j] = col1; }
      }
#pragma unroll
    for (int d = 1; d < 16; d <<= 1) {
#pragma unroll
      for (int j = 0; j < 8; ++j) {
        float om1 = __shfl_xor(m1v[j], d);
        float om2 = __shfl_xor(m2v[j], d);
        int   oi  = __shfl_xor(i1v[j], d);
        if (om1 > m1v[j] || (om1 == m1v[j] && oi < i1v[j])) {
          m2v[j] = fmaxf(m1v[j], om2); m1v[j] = om1; i1v[j] = oi;
        } else {
          m2v[j] = fmaxf(m2v[j], om1);
        }
      }
    }
    if (cc == 0) {
#pragma unroll
      for (int rt = 0; rt < 2; ++rt)
#pragma unroll
        for (int i = 0; i < 4; ++i) {
          const int j = rt * 4 + i;
          const int row = wr * 32 + rt * 16 + q * 4 + i;
          sm1[row * 4 + wcg] = m1v[j];
          sm2[row * 4 + wcg] = m2v[j];
          si1[row * 4 + wcg] = i1v[j];
        }
    }
  }
  __syncthreads();

  float lossAcc = 0.f, accAcc = 0.f;
  if (tid < RPB) {
    const int row = tid, R = rbase + row;
    float m1 = -3.4e38f, m2 = -3.4e38f; int i1 = 0;
#pragma unroll
    for (int g = 0; g < 4; ++g) {
      float a1 = sm1[row * 4 + g], a2 = sm2[row * 4 + g];
      int ai = si1[row * 4 + g];
      if (a1 > m1) { m2 = fmaxf(m1, a2); m1 = a1; i1 = ai; }
      else         { m2 = fmaxf(m2, a1); }
    }
    float yh = sT[row * 132 + i1] + decb[i1];
    out[R]      = yh;
    out[BB + R] = (float)i1;
    if (m1 - m2 < DELTA) {                     // near-tie: fp64 re-resolve later
      unsigned p = atomicAdd(counter, 1u);
      if (p < (unsigned)FCAP) {
        float* ent = list + (size_t)p * 132;
        ((unsigned*)ent)[0] = (unsigned)R;
        const f32x4* sr = (const f32x4*)(sS + row * 128);
        f32x4* dst = (f32x4*)(ent + 4);
#pragma unroll
        for (int j = 0; j < 32; ++j) dst[j] = sr[j];
      }
    }
    float yv = y[R];
    float d  = yh - yv;
    lossAcc = d * d;
    float sg = (yh > 0.f) ? 1.f : ((yh < 0.f) ? -1.f : 0.f);
    accAcc = (sg == yv) ? 1.f : 0.f;
  }
#pragma unroll
  for (int d = 1; d < 64; d <<= 1) {
    lossAcc += __shfl_xor(lossAcc, d);
    accAcc  += __shfl_xor(accAcc, d);
  }
  if (tid == 0) {
    atomicAdd(&out[2*BB],     lossAcc * (1.f / BB));
    atomicAdd(&out[2*BB + 1], accAcc  * (1.f / BB));
  }
}

// ---------------------------------------------------------------------------
// Fixup v2: one wave per flagged row. Reads the dumped approx s-row, selects
// candidate cols within (m1 - 2*DELTA), recomputes ONLY those (typically 1-3)
// in fp64 (coalesced 1KB loads), picks the true argmax, recomputes y_hat in
// fp64, patches out + loss/accuracy atomics.
// ---------------------------------------------------------------------------
__global__ __launch_bounds__(64) void fixup_kernel(
    const float* __restrict__ x, const float* __restrict__ y,
    const float* __restrict__ encW, const float* __restrict__ encb,
    const float* __restrict__ decW, const float* __restrict__ decb,
    float* __restrict__ out,
    const unsigned int* __restrict__ counter, const float* __restrict__ list)
{
  int n = (int)*counter;
  if (n > FCAP) n = FCAP;
  const int l = threadIdx.x;
  for (int e = blockIdx.x; e < n; e += gridDim.x) {
    const float* ent = list + (size_t)e * 132;
    const int R = (int)((const unsigned*)ent)[0];
    const float s0 = ent[4 + 2 * l], s1 = ent[5 + 2 * l];
    float m = fmaxf(s0, s1);
#pragma unroll
    for (int d = 1; d < 64; d <<= 1) m = fmaxf(m, __shfl_xor(m, d));
    const float win = m - 2.0f * DELTA;
    unsigned long long mm0 = __ballot(s0 >= win);
    unsigned long long mm1 = __ballot(s1 >= win);
    const float* xr = x + (size_t)R * DD;
    double best = -1e300; int bk = KK;
    while (mm0 | mm1) {
      int c;
      if (mm0) { int b = __builtin_ctzll(mm0); mm0 &= mm0 - 1; c = 2 * b; }
      else     { int b = __builtin_ctzll(mm1); mm1 &= mm1 - 1; c = 2 * b + 1; }
      const float* wp = encW + (size_t)c * DD;
      double s = 0.0;
#pragma unroll
      for (int j = 0; j < 8; ++j) {
        f32x4 wv = *(const f32x4*)(wp + j * 256 + l * 4);
        f32x4 xv = *(const f32x4*)(xr + j * 256 + l * 4);
        s = fma((double)xv[0], (double)wv[0], s);
        s = fma((double)xv[1], (double)wv[1], s);
        s = fma((double)xv[2], (double)wv[2], s);
        s = fma((double)xv[3], (double)wv[3], s);
      }
#pragma unroll
      for (int d = 1; d < 64; d <<= 1) s += __shfl_xor(s, d);
      s += (double)encb[c];
      if (s > best || (s == best && c < bk)) { best = s; bk = c; }
    }
    // dec dot in fp64
    const float* dr = decW + (size_t)bk * DD;
    double t = 0.0;
#pragma unroll
    for (int j = 0; j < 8; ++j) {
      f32x4 wv = *(const f32x4*)(dr + j * 256 + l * 4);
      f32x4 xv = *(const f32x4*)(xr + j * 256 + l * 4);
      t = fma((double)xv[0], (double)wv[0], t);
      t = fma((double)xv[1], (double)wv[1], t);
      t = fma((double)xv[2], (double)wv[2], t);
      t = fma((double)xv[3], (double)wv[3], t);
    }
#pragma unroll
    for (int d = 1; d < 64; d <<= 1) t += __shfl_xor(t, d);
    if (l == 0) {
      float yh = (float)(t + (double)decb[bk]);
      float yv = y[R];
      float old = out[R];
      float dn = yh - yv, dol = old - yv;
      atomicAdd(&out[2*BB], (dn*dn - dol*dol) * (1.f / BB));
      float sgn = (yh  > 0.f) ? 1.f : ((yh  < 0.f) ? -1.f : 0.f);
      float sgo = (old > 0.f) ? 1.f : ((old < 0.f) ? -1.f : 0.f);
      float mn = (sgn == yv) ? 1.f : 0.f;
      float mo = (sgo == yv) ? 1.f : 0.f;
      atomicAdd(&out[2*BB + 1], (mn - mo) * (1.f / BB));
      out[R]      = yh;
      out[BB + R] = (float)bk;
    }
  }
}

extern "C" void kernel_launch(void* const* d_in, const int* in_sizes, int n_in,
                              void* d_out, int out_size, void* d_ws, size_t ws_size,
                              hipStream_t stream)
{
  const float* x    = (const float*)d_in[0];
  const float* y    = (const float*)d_in[1];
  // d_in[2] = z (unused by the reference computation)
  const float* encW = (const float*)d_in[3];
  const float* encb = (const float*)d_in[4];
  const float* decW = (const float*)d_in[5];   // [1,128,2048] -> row-major [128][2048]
  const float* decb = (const float*)d_in[6];
  float* out = (float*)d_out;

  unsigned char* ws = (unsigned char*)d_ws;
  unsigned short* wEh = (unsigned short*)ws;                 // 512 KB
  unsigned short* wDh = (unsigned short*)(ws + 524288);      // 512 KB
  unsigned int* counter = (unsigned int*)(ws + 1048576);
  float* list = (float*)(ws + 1048592);                      // FCAP x 132 floats

  prep_kernel<<<128, 256, 0, stream>>>(encW, decW, wEh, wDh, out, counter);
  main_kernel<<<NBLK, 512, 0, stream>>>(x, y, encb, decb, wEh, wDh,
                                        out, counter, list);
  fixup_kernel<<<512, 64, 0, stream>>>(x, y, encW, encb, decW, decb,
                                       out, counter, list);
}